// Round 18
// baseline (48.168 us; speedup 1.0000x reference)
//
#include <hip/hip_runtime.h>
#include <hip/hip_bf16.h>
#include <cstddef>

#define NAGENT 8
#define DIN    128
#define HID    64
#define NACT   16

typedef __attribute__((ext_vector_type(8))) short bf16x8;
typedef __attribute__((ext_vector_type(4))) float f32x4;

__device__ __forceinline__ short f2bf(float f) {
    __hip_bfloat16 h = __float2bfloat16(f);      // RNE; pairs pack to v_cvt_pk_bf16_f32
    union { __hip_bfloat16 h; short s; } u; u.h = h;
    return u.s;
}
__device__ __forceinline__ float bf2f(unsigned short u) {
    union { unsigned u; float f; } v; v.u = ((unsigned)u) << 16; return v.f;
}
__device__ __forceinline__ float sigmoid_f(float v) { return 1.0f / (1.0f + __expf(-v)); }
__device__ __forceinline__ float tanh_f(float v) {
    v = fminf(fmaxf(v, -15.0f), 15.0f);
    float e = __expf(2.0f * v);
    return 1.0f - 2.0f / (e + 1.0f);
}
__device__ __forceinline__ bf16x8 cvt8pair(float4 v0, float4 v1) {
    bf16x8 r;
    r[0] = f2bf(v0.x); r[1] = f2bf(v0.y); r[2] = f2bf(v0.z); r[3] = f2bf(v0.w);
    r[4] = f2bf(v1.x); r[5] = f2bf(v1.y); r[6] = f2bf(v1.z); r[7] = f2bf(v1.w);
    return r;
}
__device__ __forceinline__ void gload_lds16(const void* g, void* l) {
    __builtin_amdgcn_global_load_lds(
        (const __attribute__((address_space(1))) unsigned int*)g,
        (__attribute__((address_space(3))) unsigned int*)l, 16, 0, 0);
}

// ---------------- weight fp32 -> bf16 fragment-major packing ----------------
// Per-agent packed layout (shorts), base a*33792; 1KB rounds (512 shorts):
//   W1  rounds  0..15 : f=(n*4+k)        -> W1[a][n*16+lr][k*32+lk*8]
//   Wih rounds 16..39 : 16+(g*4+n)*2+kk  -> Wih[a][g*64+n*16+lr][kk*32+lk*8]
//   Whh rounds 40..63 : 40+(g*4+n)*2+kk  -> Whh[...]
//   W2  rounds 64..65 : 64+kk            -> W2[a][lr][kk*32+lk*8]
extern "C" __global__ void __launch_bounds__(256)
conv_weights_packed(const float* __restrict__ W1, const float* __restrict__ Wih,
                    const float* __restrict__ Whh, const float* __restrict__ W2,
                    short* __restrict__ ws)
{
    const int a = blockIdx.y;
    const int c = blockIdx.x * 256 + threadIdx.x;
    if (c >= 4224) return;
    const int lane = c & 63, lr = lane & 15, lk = lane >> 4;
    const float* src;
    if (c < 1024) {
        int n = c >> 8, k = (c >> 6) & 3;
        src = W1 + a * 8192 + (n * 16 + lr) * 128 + k * 32 + lk * 8;
    } else if (c < 2560) {
        int idx = (c - 1024) >> 6;
        int g = idx >> 3, n = (idx >> 1) & 3, kk = idx & 1;
        src = Wih + a * 12288 + (g * 64 + n * 16 + lr) * 64 + kk * 32 + lk * 8;
    } else if (c < 4096) {
        int idx = (c - 2560) >> 6;
        int g = idx >> 3, n = (idx >> 1) & 3, kk = idx & 1;
        src = Whh + a * 12288 + (g * 64 + n * 16 + lr) * 64 + kk * 32 + lk * 8;
    } else {
        int kk = (c - 4096) >> 6;
        src = W2 + a * 1024 + lr * 64 + kk * 32 + lk * 8;
    }
    float4 v0 = ((const float4*)src)[0];
    float4 v1 = ((const float4*)src)[1];
    bf16x8 o = cvt8pair(v0, v1);
    *(bf16x8*)(ws + (size_t)a * 33792 + (size_t)c * 8) = o;
}

// ---------------- main fused kernel ----------------
// r17 base (47.9us: T3-correct double-buffered staging, 11 phases, 64-VGPR
// tier, agent-per-CU) + round-18 bundle:
//  (a) hout via LDS-bounce: in-loop scalar stores removed (they were drained
//      by every barrier's vmcnt(0)); after the gate loop, h_new (bf16, already
//      in zs) is re-read in coalesced order and written as 4x
//      global_store_dwordx4 per thread — one addr chain, 64B segments.
//  (b) T5: s_setprio(1) around each 6-MFMA cluster (r17's phase-split
//      schedule is the catalog prerequisite; +21-25% on 8-phase GEMM).
//  (c) tanh as 1-2/(e+1).
extern "C" __global__ void __launch_bounds__(256, 4)
rnn_main(const float* __restrict__ x,     // [B*A, D]
         const float* __restrict__ hin,   // [B, A, H]
         const float* __restrict__ b1, const float* __restrict__ bih,
         const float* __restrict__ bhh, const float* __restrict__ b2,
         const short* __restrict__ wsp,   // packed bf16 weights
         float* __restrict__ qout,        // [B*A, NACT]
         float* __restrict__ hout)        // [B, A, H]
{
    const int bid  = blockIdx.x;
    const int a    = bid & 7;             // one agent per CU
    const int t    = threadIdx.x;
    const int wid  = t >> 6;              // 0..3
    const int lane = t & 63;
    const int lr   = lane & 15;
    const int lk   = lane >> 4;

    __shared__ short wbuf[2 * 3072];      // 12 KB double-buffered weight stage
    __shared__ short zs[4 * 1024];        // 8 KB per-wave transpose buffers
    char* zb = (char*)(zs + wid * 1024);
    const char* wb0 = (const char*)wbuf;          // buf0 bytes
    const char* wb1 = (const char*)(wbuf + 3072); // buf1 bytes

    const short* wsA = wsp + (size_t)a * 33792;
    const int tile = (bid >> 3) * 4 + wid;
    const int arow = tile * 16 + lr;

    #define STAGE6(dstbuf, REXPR)                                                   \
        { int s = wid;  int rr = (REXPR);                                           \
          gload_lds16(wsA + (size_t)rr * 512 + lane * 8, (dstbuf) + s * 512);       \
          if (wid < 2) { s = wid + 4; rr = (REXPR);                                 \
            gload_lds16(wsA + (size_t)rr * 512 + lane * 8, (dstbuf) + s * 512); } }

    // ---- prologue: stage p0 (fc1 rounds 0..5) into buf0 ----
    STAGE6(wbuf, s)

    const float* xrow = x + ((size_t)arow * NAGENT + a) * DIN + lk * 8;
    const float* hrow = hin + ((size_t)arow * NAGENT + a) * HID + lk * 8;
    bf16x8 xf[4];
    #pragma unroll
    for (int k = 0; k < 4; ++k)
        xf[k] = cvt8pair(*(const float4*)(xrow + k * 32),
                         *(const float4*)(xrow + k * 32 + 4));
    bf16x8 hf0 = cvt8pair(*(const float4*)(hrow),      *(const float4*)(hrow + 4));
    bf16x8 hf1 = cvt8pair(*(const float4*)(hrow + 32), *(const float4*)(hrow + 36));
    float b1v[4];
    #pragma unroll
    for (int n = 0; n < 4; ++n) b1v[n] = b1[a * HID + n * 16 + lr];

    f32x4 acc1[4];
    #pragma unroll
    for (int n = 0; n < 4; ++n) acc1[n] = (f32x4){0.f, 0.f, 0.f, 0.f};

    __syncthreads();                      // buf0[p0] ready

    // ---- p0: stage p1 -> buf1; compute fc1 frags 0..5 from buf0 ----
    STAGE6(wbuf + 3072, 6 + s)
    __builtin_amdgcn_s_setprio(1);
    #pragma unroll
    for (int s = 0; s < 6; ++s) {
        bf16x8 w = *(const bf16x8*)(wb0 + s * 1024 + lane * 16);
        acc1[s >> 2] = __builtin_amdgcn_mfma_f32_16x16x32_bf16(xf[s & 3], w, acc1[s >> 2], 0, 0, 0);
    }
    __builtin_amdgcn_s_setprio(0);
    __syncthreads();

    // ---- p1: stage p2 (rounds 12..15) -> buf0; compute frags 6..11 from buf1 ----
    gload_lds16(wsA + (size_t)(12 + wid) * 512 + lane * 8, wbuf + wid * 512);
    __builtin_amdgcn_s_setprio(1);
    #pragma unroll
    for (int s = 0; s < 6; ++s) {
        int f = 6 + s;
        bf16x8 w = *(const bf16x8*)(wb1 + s * 1024 + lane * 16);
        acc1[f >> 2] = __builtin_amdgcn_mfma_f32_16x16x32_bf16(xf[f & 3], w, acc1[f >> 2], 0, 0, 0);
    }
    __builtin_amdgcn_s_setprio(0);
    __syncthreads();

    // ---- p2: stage i-path(n=0) -> buf1; compute frags 12..15 from buf0; z1 -> zs ----
    STAGE6(wbuf + 3072, 16 + 0 * 2 + (s >> 1) * 8 + (s & 1))
    __builtin_amdgcn_s_setprio(1);
    #pragma unroll
    for (int s = 0; s < 4; ++s) {
        bf16x8 w = *(const bf16x8*)(wb0 + s * 1024 + lane * 16);
        acc1[3] = __builtin_amdgcn_mfma_f32_16x16x32_bf16(xf[s], w, acc1[3], 0, 0, 0);
    }
    __builtin_amdgcn_s_setprio(0);
    #pragma unroll
    for (int n = 0; n < 4; ++n)
        #pragma unroll
        for (int j = 0; j < 4; ++j) {
            int row = lk * 4 + j, col = n * 16 + lr;
            *(short*)(zb + row * 128 + ((col * 2) ^ ((row & 7) << 4))) =
                f2bf(fmaxf(acc1[n][j] + b1v[n], 0.0f));
        }
    __syncthreads();                      // buf1[i0] ready

    bf16x8 za0 = *(const bf16x8*)(zb + lr * 128 + ((0 * 64 + lk * 16) ^ ((lr & 7) << 4)));
    bf16x8 za1 = *(const bf16x8*)(zb + lr * 128 + ((1 * 64 + lk * 16) ^ ((lr & 7) << 4)));

    // ---- gates: per col-block n: {i-phase reads buf1, stages h(n)->buf0;
    //                               h-phase reads buf0, stages i(n+1)->buf1} ----
    #pragma unroll 1
    for (int n = 0; n < 4; ++n) {
        // i-phase
        STAGE6(wbuf, 40 + n * 2 + (s >> 1) * 8 + (s & 1))
        float hp[4];
        #pragma unroll
        for (int j = 0; j < 4; ++j)
            hp[j] = hin[((size_t)(tile * 16 + lk * 4 + j) * NAGENT + a) * HID + n * 16 + lr];
        float bsr  = bih[a * 192 +   0 + n * 16 + lr] + bhh[a * 192 +   0 + n * 16 + lr];
        float bsz  = bih[a * 192 +  64 + n * 16 + lr] + bhh[a * 192 +  64 + n * 16 + lr];
        float bin_ = bih[a * 192 + 128 + n * 16 + lr];
        float bhn_ = bhh[a * 192 + 128 + n * 16 + lr];

        f32x4 aI0 = (f32x4){0.f,0.f,0.f,0.f}, aI1 = aI0, aI2 = aI0;
        {
            bf16x8 w0 = *(const bf16x8*)(wb1 + 0 * 1024 + lane * 16);
            bf16x8 w1 = *(const bf16x8*)(wb1 + 1 * 1024 + lane * 16);
            bf16x8 w2 = *(const bf16x8*)(wb1 + 2 * 1024 + lane * 16);
            bf16x8 w3 = *(const bf16x8*)(wb1 + 3 * 1024 + lane * 16);
            bf16x8 w4 = *(const bf16x8*)(wb1 + 4 * 1024 + lane * 16);
            bf16x8 w5 = *(const bf16x8*)(wb1 + 5 * 1024 + lane * 16);
            __builtin_amdgcn_s_setprio(1);
            aI0 = __builtin_amdgcn_mfma_f32_16x16x32_bf16(za0, w0, aI0, 0, 0, 0);
            aI0 = __builtin_amdgcn_mfma_f32_16x16x32_bf16(za1, w1, aI0, 0, 0, 0);
            aI1 = __builtin_amdgcn_mfma_f32_16x16x32_bf16(za0, w2, aI1, 0, 0, 0);
            aI1 = __builtin_amdgcn_mfma_f32_16x16x32_bf16(za1, w3, aI1, 0, 0, 0);
            aI2 = __builtin_amdgcn_mfma_f32_16x16x32_bf16(za0, w4, aI2, 0, 0, 0);
            aI2 = __builtin_amdgcn_mfma_f32_16x16x32_bf16(za1, w5, aI2, 0, 0, 0);
            __builtin_amdgcn_s_setprio(0);
        }
        __syncthreads();                  // buf0[h(n)] ready

        // h-phase
        if (n < 3) {
            STAGE6(wbuf + 3072, 16 + (n + 1) * 2 + (s >> 1) * 8 + (s & 1))
        }
        f32x4 aH0 = (f32x4){0.f,0.f,0.f,0.f}, aH1 = aH0, aH2 = aH0;
        {
            bf16x8 w0 = *(const bf16x8*)(wb0 + 0 * 1024 + lane * 16);
            bf16x8 w1 = *(const bf16x8*)(wb0 + 1 * 1024 + lane * 16);
            bf16x8 w2 = *(const bf16x8*)(wb0 + 2 * 1024 + lane * 16);
            bf16x8 w3 = *(const bf16x8*)(wb0 + 3 * 1024 + lane * 16);
            bf16x8 w4 = *(const bf16x8*)(wb0 + 4 * 1024 + lane * 16);
            bf16x8 w5 = *(const bf16x8*)(wb0 + 5 * 1024 + lane * 16);
            __builtin_amdgcn_s_setprio(1);
            aH0 = __builtin_amdgcn_mfma_f32_16x16x32_bf16(hf0, w0, aH0, 0, 0, 0);
            aH0 = __builtin_amdgcn_mfma_f32_16x16x32_bf16(hf1, w1, aH0, 0, 0, 0);
            aH1 = __builtin_amdgcn_mfma_f32_16x16x32_bf16(hf0, w2, aH1, 0, 0, 0);
            aH1 = __builtin_amdgcn_mfma_f32_16x16x32_bf16(hf1, w3, aH1, 0, 0, 0);
            aH2 = __builtin_amdgcn_mfma_f32_16x16x32_bf16(hf0, w4, aH2, 0, 0, 0);
            aH2 = __builtin_amdgcn_mfma_f32_16x16x32_bf16(hf1, w5, aH2, 0, 0, 0);
            __builtin_amdgcn_s_setprio(0);
        }
        // elementwise: h_new -> zs only (hout written later via LDS bounce,
        // so no store acks get drained by the phase barriers)
        #pragma unroll
        for (int j = 0; j < 4; ++j) {
            int row = lk * 4 + j, col = n * 16 + lr;
            float r  = sigmoid_f(aI0[j] + aH0[j] + bsr);
            float zv = sigmoid_f(aI1[j] + aH1[j] + bsz);
            float nn = tanh_f((aI2[j] + bin_) + r * (aH2[j] + bhn_));
            float hv = (1.0f - zv) * nn + zv * hp[j];
            *(short*)(zb + row * 128 + ((col * 2) ^ ((row & 7) << 4))) = f2bf(hv);
        }
        if (n < 3) __syncthreads();       // buf1[i(n+1)] ready
    }

    // ---- fc2: q = h_new @ W2^T + b2 (W2 from L2; zs is per-wave) ----
    {
        float bq = b2[a * NACT + lr];
        f32x4 q = (f32x4){bq, bq, bq, bq};
        bf16x8 ha0 = *(const bf16x8*)(zb + lr * 128 + ((0 * 64 + lk * 16) ^ ((lr & 7) << 4)));
        bf16x8 ha1 = *(const bf16x8*)(zb + lr * 128 + ((1 * 64 + lk * 16) ^ ((lr & 7) << 4)));
        bf16x8 w2f0 = *(const bf16x8*)(wsA + 32768 + (0 * 64 + lane) * 8);
        bf16x8 w2f1 = *(const bf16x8*)(wsA + 32768 + (1 * 64 + lane) * 8);
        q = __builtin_amdgcn_mfma_f32_16x16x32_bf16(ha0, w2f0, q, 0, 0, 0);
        q = __builtin_amdgcn_mfma_f32_16x16x32_bf16(ha1, w2f1, q, 0, 0, 0);
        #pragma unroll
        for (int j = 0; j < 4; ++j)
            qout[((size_t)(tile * 16 + lk * 4 + j) * NAGENT + a) * NACT + lr] = q[j];
    }

    // ---- hout LDS-bounce: coalesced vectorized store of h_new ----
    // lane l: row = l>>2, cols (l&3)*4 + i*16 .. +3  (64B segments per 4 lanes)
    {
        int row = lane >> 2;
        int c0  = (lane & 3) * 4;
        float* hb = hout + ((size_t)(tile * 16 + row) * NAGENT + a) * HID + c0;
        #pragma unroll
        for (int i = 0; i < 4; ++i) {
            int cb = (c0 + i * 16) * 2;
            unsigned long long v =
                *(const unsigned long long*)(zb + row * 128 + (cb ^ ((row & 7) << 4)));
            float4 o;
            o.x = bf2f((unsigned short)(v));
            o.y = bf2f((unsigned short)(v >> 16));
            o.z = bf2f((unsigned short)(v >> 32));
            o.w = bf2f((unsigned short)(v >> 48));
            *(float4*)(hb + i * 16) = o;
        }
    }
    #undef STAGE6
}

extern "C" void kernel_launch(void* const* d_in, const int* in_sizes, int n_in,
                              void* d_out, int out_size, void* d_ws, size_t ws_size,
                              hipStream_t stream)
{
    const float* x   = (const float*)d_in[0];
    const float* hin = (const float*)d_in[1];
    const float* W1  = (const float*)d_in[2];
    const float* b1  = (const float*)d_in[3];
    const float* Wih = (const float*)d_in[4];
    const float* bih = (const float*)d_in[5];
    const float* Whh = (const float*)d_in[6];
    const float* bhh = (const float*)d_in[7];
    const float* W2  = (const float*)d_in[8];
    const float* b2  = (const float*)d_in[9];

    const int B = in_sizes[0] / (NAGENT * DIN);   // 16384

    float* qout = (float*)d_out;                              // [B*A, NACT]
    float* hout = (float*)d_out + (size_t)B * NAGENT * NACT;  // [B, A, H]

    short* wsp = (short*)d_ws;                                // 540,672 B packed

    conv_weights_packed<<<dim3(17, NAGENT), 256, 0, stream>>>(W1, Wih, Whh, W2, wsp);

    // 1-D grid: 2048 blocks; agent = bid & 7 (one agent per CU under linear
    // round-robin dispatch since 256 % 8 == 0).
    dim3 grid((B / 64) * NAGENT);
    rnn_main<<<grid, 256, 0, stream>>>(x, hin, b1, bih, bhh, b2, wsp, qout, hout);
}